// Round 24
// baseline (279.718 us; speedup 1.0000x reference)
//
#include <hip/hip_runtime.h>

typedef __bf16 bf16;
typedef bf16 bf16x4 __attribute__((ext_vector_type(4)));
typedef bf16 bf16x8 __attribute__((ext_vector_type(8)));
typedef float f32x4 __attribute__((ext_vector_type(4)));

// ws layout (bf16 element offsets):
//   PK1  [4][4][4][64][8] = 32768    GEMM1 weights, fragment-packed
//   PK2  [4][8][4][64][8] = 65536    W1
//   PK3  [4][8][4][64][8] = 65536    W2
//   QGF  float[64][256]   at bf16-offset 163840
#define WS_PK1    0
#define WS_PK2    32768
#define WS_PK3    98304
#define WS_QGF_B  163840

// ---------- prep: pack weights into per-(cg,kk,ai) contiguous 1KB fragments ----------
__global__ void prep_weights(const float* __restrict__ Wrel,
                             const float* __restrict__ Wnode,
                             const float* __restrict__ W1,
                             const float* __restrict__ W2,
                             bf16* __restrict__ ws) {
  int id = blockIdx.x * 256 + threadIdx.x;
  if (id < 32768) {                       // PK1: cg(4) kk(4) ai(4) l(64) j(8)
    int cg = id >> 13, rem = id & 8191;
    int kk = rem >> 11;
    int ai = (rem >> 9) & 3;
    int l  = (rem >> 3) & 63;
    int j  = rem & 7;
    int n  = (cg & 1) * 64 + ai * 16 + (l & 15);
    int k  = kk * 32 + (l >> 4) * 8 + j;
    const float* src = (cg >> 1) ? Wnode : Wrel;
    ws[WS_PK1 + id] = (bf16)src[k * 128 + n];
  } else if (id < 98304) {                // PK2: cg(4) kk(8) ai(4) l(64) j(8)
    int t = id - 32768;
    int cg = t >> 14, rem = t & 16383;
    int kk = rem >> 11;
    int ai = (rem >> 9) & 3;
    int l  = (rem >> 3) & 63;
    int j  = rem & 7;
    int n  = cg * 64 + ai * 16 + (l & 15);
    int k  = kk * 32 + (l >> 4) * 8 + j;
    ws[WS_PK2 + t] = (bf16)W1[k * 256 + n];
  } else if (id < 163840) {               // PK3
    int t = id - 98304;
    int cg = t >> 14, rem = t & 16383;
    int kk = rem >> 11;
    int ai = (rem >> 9) & 3;
    int l  = (rem >> 3) & 63;
    int j  = rem & 7;
    int n  = cg * 64 + ai * 16 + (l & 15);
    int k  = kk * 32 + (l >> 4) * 8 + j;
    ws[WS_PK3 + t] = (bf16)W2[k * 256 + n];
  }
}

// ---------- prep: qg[64][256] = sigmoid(question @ W_qgate), fp32 ----------
__global__ void prep_qg(const float* __restrict__ question,
                        const float* __restrict__ Wq,
                        float* __restrict__ qgf) {
  int b = blockIdx.x, c = threadIdx.x;
  float s = 0.f;
#pragma unroll 8
  for (int k = 0; k < 128; ++k) s += question[b * 128 + k] * Wq[k * 256 + c];
  qgf[b * 256 + c] = 1.f / (1.f + expf(-s));
}

// tanh-form GELU, exp2-direct. max |diff vs erf-GELU| ~5e-4 << 1.23e-2 budget.
__device__ __forceinline__ float gelu_fast(float x) {
  float m = x * x;
  float t = fmaf(0.10294537f, m, 2.30220790f);
  float e = __builtin_amdgcn_exp2f(t * x);
  float r = __builtin_amdgcn_rcpf(e + 1.f);
  return x - x * r;
}

typedef __attribute__((address_space(1))) const void gq_t;
typedef __attribute__((address_space(3))) void lq_t;
#define GLD16(g, s) __builtin_amdgcn_global_load_lds((gq_t*)(g), (lq_t*)(s), 16, 0, 0)
// sched_barrier mask 0xF = ALU|VALU|SALU|MFMA may cross; DS/VMEM pinned.
#define SB() __builtin_amdgcn_sched_barrier(0xF)
#define WAIT_VM4()   { asm volatile("s_waitcnt vmcnt(4)" ::: "memory"); SB(); }
#define WAIT_VM0()   { asm volatile("s_waitcnt vmcnt(0)" ::: "memory"); SB(); }
#define WAIT_LGKM0() { asm volatile("s_waitcnt lgkmcnt(0)" ::: "memory"); SB(); }
#define BAR() __builtin_amdgcn_s_barrier()

// ---------- main: 64 edges/block, 4 waves (1 cg each), 2 blocks/CU ----------
// R12/R19 champion: wave-private 2-slot weight FIFO in LDS fed by
// global_load_lds, depth-2 counted vmcnt (never drained mid-loop);
// swapped-operand MFMA (D = W x X^T); exp2 GELU; fp32 gate table.
// R24: nontemporal rel-token LOADS only (FETCH 211->197 MB, R23-verified);
// output stores back to normal cached stores (R23's nt-store inflated
// WRITE 401->530 MB via broken L2 write-combining).
__global__ __launch_bounds__(256, 2) void fused_main(
    const float* __restrict__ rel_tok,   // [E,128]
    const float* __restrict__ node_tok,  // [N,128]
    const int*   __restrict__ tail_idx,  // edge_index + E
    const int*   __restrict__ ebatch,    // [E]
    const bf16*  __restrict__ pk1,
    const bf16*  __restrict__ pk2,
    const bf16*  __restrict__ pk3,
    const float* __restrict__ qgf,       // [64][256] fp32
    const float* __restrict__ b1,
    const float* __restrict__ b2,
    float* __restrict__ out)             // [E,256]
{
  // s_buf 32KB union: tokens [2][64][128] bf16 (h*16384 + e*256 + swz)
  //                   AK/H   [64][256]    bf16 (e*512 + swz)
  // s_w   32KB: [slot 2][cg 4][4KB]
  __shared__ char  s_buf[32768];
  __shared__ char  s_w[32768];
  __shared__ float s_bias[512];          // b1 | b2

  const int tid = threadIdx.x;
  const int cg  = tid >> 6;       // wave = col group, cols [cg*64, cg*64+64)
  const int l   = tid & 63;
  const int lo  = l & 15;
  const int hi  = l >> 4;
  const int base = blockIdx.x * 64;
  const int h1  = cg >> 1;        // GEMM1 half (0=rel, 1=node)

  auto issue_step = [&](int s) {   // s compile-time after unroll
    const bf16* g;
    if (s < 4)       g = pk1 + cg * 8192  + s * 2048;
    else if (s < 12) g = pk2 + cg * 16384 + (s - 4) * 2048;
    else             g = pk3 + cg * 16384 + (s - 12) * 2048;
    g += l * 8;
    char* d = s_w + (s & 1) * 16384 + cg * 4096;
#pragma unroll
    for (int ai = 0; ai < 4; ++ai) GLD16(g + ai * 512, d + ai * 1024);
  };

  // ---- pre-FIFO VMEM: fp32 gate fragments (64 VGPR, dead by B_c), biases -> LDS ----
  int ebv[4];
#pragma unroll
  for (int bj = 0; bj < 4; ++bj) ebv[bj] = ebatch[base + bj * 16 + lo];
  f32x4 gv[4][4];
#pragma unroll
  for (int bj = 0; bj < 4; ++bj)
#pragma unroll
    for (int ai = 0; ai < 4; ++ai)
      gv[bj][ai] = *(const f32x4*)(qgf + ebv[bj] * 256 + cg * 64 + ai * 16 + hi * 4);
  s_bias[tid]       = b1[tid];
  s_bias[256 + tid] = b2[tid];

  // ---- stage tokens -> LDS bf16 ((row&15) XOR swizzle) ----
  {
    const f32x4* g = (const f32x4*)rel_tok + (size_t)base * 32;
#pragma unroll
    for (int i = 0; i < 8; ++i) {
      int idx = tid + i * 256;          // over [64][32] float4
      int row = idx >> 5, c4 = idx & 31;
      f32x4 v = __builtin_nontemporal_load(g + idx);   // read-once stream
      bf16x4 b; b[0] = (bf16)v[0]; b[1] = (bf16)v[1]; b[2] = (bf16)v[2]; b[3] = (bf16)v[3];
      int off = row * 256 + ((c4 * 8) ^ ((row & 15) << 4));
      *(bf16x4*)(s_buf + off) = b;
    }
#pragma unroll
    for (int i = 0; i < 8; ++i) {
      int idx = tid + i * 256;
      int row = idx >> 5, c4 = idx & 31;
      int tail = tail_idx[base + row];  // 32 lanes same addr
      f32x4 v = ((const f32x4*)node_tok)[(size_t)tail * 32 + c4];  // reused: cache normally
      bf16x4 b; b[0] = (bf16)v[0]; b[1] = (bf16)v[1]; b[2] = (bf16)v[2]; b[3] = (bf16)v[3];
      int off = 16384 + row * 256 + ((c4 * 8) ^ ((row & 15) << 4));
      *(bf16x4*)(s_buf + off) = b;
    }
  }

  WAIT_VM0();                           // clean vmcnt slate before FIFO starts
  issue_step(0);
  issue_step(1);
  WAIT_LGKM0();                         // token/bias LDS writes done
  BAR();                                // B_a: tokens + biases visible

  const f32x4 zero4 = {0.f, 0.f, 0.f, 0.f};
  const int wb = cg * 4096 + l * 16;    // lane's read offset within a slot half

  // ================= GEMM1: steps 0..3, b from token region =================
  f32x4 acc1[4][4];
#pragma unroll
  for (int ai = 0; ai < 4; ++ai)
#pragma unroll
    for (int bj = 0; bj < 4; ++bj) acc1[ai][bj] = zero4;

#pragma unroll
  for (int kk = 0; kk < 4; ++kk) {
    const int s = kk;
    WAIT_VM4();                         // step s resident (s+1 in flight)
    bf16x8 a[4];
#pragma unroll
    for (int ai = 0; ai < 4; ++ai)
      a[ai] = *(const bf16x8*)(s_w + (s & 1) * 16384 + wb + ai * 1024);
    WAIT_LGKM0();                       // a[] in regs before slot reuse
    issue_step(s + 2);
    __builtin_amdgcn_s_setprio(1);
#pragma unroll
    for (int bj = 0; bj < 4; ++bj) {
      int e = bj * 16 + lo;
      bf16x8 b = *(const bf16x8*)(s_buf + h1 * 16384 + e * 256 +
                                  ((kk * 64 + hi * 16) ^ ((e & 15) << 4)));
#pragma unroll
      for (int ai = 0; ai < 4; ++ai)
        acc1[ai][bj] = __builtin_amdgcn_mfma_f32_16x16x32_bf16(a[ai], b, acc1[ai][bj], 0, 0, 0);
    }
    __builtin_amdgcn_s_setprio(0);
  }
  BAR();                                // B_b: all token reads done

  // gate + pack -> AK over token buffer (fp32 gate: no cvt)
#pragma unroll
  for (int bj = 0; bj < 4; ++bj) {
    int e = bj * 16 + lo;
#pragma unroll
    for (int ai = 0; ai < 4; ++ai) {
      int col0 = cg * 64 + ai * 16 + hi * 4;
      bf16x4 pk;
      pk[0] = (bf16)(acc1[ai][bj][0] * gv[bj][ai][0]);
      pk[1] = (bf16)(acc1[ai][bj][1] * gv[bj][ai][1]);
      pk[2] = (bf16)(acc1[ai][bj][2] * gv[bj][ai][2]);
      pk[3] = (bf16)(acc1[ai][bj][3] * gv[bj][ai][3]);
      int off = e * 512 + ((2 * col0) ^ ((e & 15) << 4));
      *(bf16x4*)(s_buf + off) = pk;
    }
  }
  WAIT_LGKM0();
  BAR();                                // B_c: AK visible

  // ================= GEMM2: steps 4..11, b from AK =================
  f32x4 acc2[4][4];
#pragma unroll
  for (int ai = 0; ai < 4; ++ai)
#pragma unroll
    for (int bj = 0; bj < 4; ++bj) acc2[ai][bj] = zero4;

#pragma unroll
  for (int kk = 0; kk < 8; ++kk) {
    const int s = 4 + kk;
    WAIT_VM4();
    bf16x8 a[4];
#pragma unroll
    for (int ai = 0; ai < 4; ++ai)
      a[ai] = *(const bf16x8*)(s_w + (s & 1) * 16384 + wb + ai * 1024);
    WAIT_LGKM0();
    issue_step(s + 2);
    __builtin_amdgcn_s_setprio(1);
#pragma unroll
    for (int bj = 0; bj < 4; ++bj) {
      int e = bj * 16 + lo;
      bf16x8 b = *(const bf16x8*)(s_buf + e * 512 +
                                  ((kk * 64 + hi * 16) ^ ((e & 15) << 4)));
#pragma unroll
      for (int ai = 0; ai < 4; ++ai)
        acc2[ai][bj] = __builtin_amdgcn_mfma_f32_16x16x32_bf16(a[ai], b, acc2[ai][bj], 0, 0, 0);
    }
    __builtin_amdgcn_s_setprio(0);
  }
  BAR();                                // B_d: all AK reads done

  // gelu + bias -> H (bias from LDS: no VMEM in FIFO window)
#pragma unroll
  for (int bj = 0; bj < 4; ++bj) {
    int e = bj * 16 + lo;
#pragma unroll
    for (int ai = 0; ai < 4; ++ai) {
      int col0 = cg * 64 + ai * 16 + hi * 4;
      f32x4 bv = *(const f32x4*)(s_bias + col0);
      bf16x4 pk;
      pk[0] = (bf16)gelu_fast(acc2[ai][bj][0] + bv[0]);
      pk[1] = (bf16)gelu_fast(acc2[ai][bj][1] + bv[1]);
      pk[2] = (bf16)gelu_fast(acc2[ai][bj][2] + bv[2]);
      pk[3] = (bf16)gelu_fast(acc2[ai][bj][3] + bv[3]);
      int off = e * 512 + ((2 * col0) ^ ((e & 15) << 4));
      *(bf16x4*)(s_buf + off) = pk;
    }
  }
  WAIT_LGKM0();
  BAR();                                // B_e: H visible

  // ================= GEMM3: steps 12..19, b from H =================
  f32x4 acc3[4][4];
#pragma unroll
  for (int ai = 0; ai < 4; ++ai)
#pragma unroll
    for (int bj = 0; bj < 4; ++bj) acc3[ai][bj] = zero4;

#pragma unroll
  for (int kk = 0; kk < 8; ++kk) {
    const int s = 12 + kk;
    if (s < 19) { WAIT_VM4(); } else { WAIT_VM0(); }
    bf16x8 a[4];
#pragma unroll
    for (int ai = 0; ai < 4; ++ai)
      a[ai] = *(const bf16x8*)(s_w + (s & 1) * 16384 + wb + ai * 1024);
    WAIT_LGKM0();
    if (s + 2 <= 19) issue_step(s + 2);
    __builtin_amdgcn_s_setprio(1);
#pragma unroll
    for (int bj = 0; bj < 4; ++bj) {
      int e = bj * 16 + lo;
      bf16x8 b = *(const bf16x8*)(s_buf + e * 512 +
                                  ((kk * 64 + hi * 16) ^ ((e & 15) << 4)));
#pragma unroll
      for (int ai = 0; ai < 4; ++ai)
        acc3[ai][bj] = __builtin_amdgcn_mfma_f32_16x16x32_bf16(a[ai], b, acc3[ai][bj], 0, 0, 0);
    }
    __builtin_amdgcn_s_setprio(0);
  }

  // bias + store (normal cached f32x4: L2 write-combining keeps WRITE=output)
#pragma unroll
  for (int bj = 0; bj < 4; ++bj) {
    int e = bj * 16 + lo;
#pragma unroll
    for (int ai = 0; ai < 4; ++ai) {
      int col0 = cg * 64 + ai * 16 + hi * 4;
      f32x4 bv = *(const f32x4*)(s_bias + 256 + col0);
      f32x4 o;
      o[0] = acc3[ai][bj][0] + bv[0];
      o[1] = acc3[ai][bj][1] + bv[1];
      o[2] = acc3[ai][bj][2] + bv[2];
      o[3] = acc3[ai][bj][3] + bv[3];
      *(f32x4*)(out + (size_t)(base + e) * 256 + col0) = o;
    }
  }
}

extern "C" void kernel_launch(void* const* d_in, const int* in_sizes, int n_in,
                              void* d_out, int out_size, void* d_ws, size_t ws_size,
                              hipStream_t stream) {
  const float* rel    = (const float*)d_in[0];
  const float* node   = (const float*)d_in[1];
  const int*   eidx   = (const int*)d_in[2];
  const float* quest  = (const float*)d_in[3];
  const int*   ebat   = (const int*)d_in[4];
  const float* Wrel   = (const float*)d_in[5];
  const float* Wnode  = (const float*)d_in[6];
  const float* Wq     = (const float*)d_in[7];
  const float* W1     = (const float*)d_in[8];
  const float* bias1  = (const float*)d_in[9];
  const float* W2     = (const float*)d_in[10];
  const float* bias2  = (const float*)d_in[11];
  float* outp = (float*)d_out;
  bf16* ws = (bf16*)d_ws;
  float* qgf = (float*)(ws + WS_QGF_B);

  const int E = in_sizes[4];  // 400000

  prep_weights<<<640, 256, 0, stream>>>(Wrel, Wnode, W1, W2, ws);
  prep_qg<<<64, 256, 0, stream>>>(quest, Wq, qgf);
  fused_main<<<E / 64, 256, 0, stream>>>(
      rel, node, eidx + E, ebat,
      ws + WS_PK1, ws + WS_PK2, ws + WS_PK3, qgf,
      bias1, bias2, outp);
}

// Round 25
// 270.390 us; speedup vs baseline: 1.0345x; 1.0345x over previous
//
#include <hip/hip_runtime.h>

typedef __bf16 bf16;
typedef bf16 bf16x4 __attribute__((ext_vector_type(4)));
typedef bf16 bf16x8 __attribute__((ext_vector_type(8)));
typedef float f32x4 __attribute__((ext_vector_type(4)));

// ws layout (bf16 element offsets):
//   PK1  [4][4][4][64][8] = 32768    GEMM1 weights, fragment-packed
//   PK2  [4][8][4][64][8] = 65536    W1
//   PK3  [4][8][4][64][8] = 65536    W2
//   QGF  float[64][256]   at bf16-offset 163840
#define WS_PK1    0
#define WS_PK2    32768
#define WS_PK3    98304
#define WS_QGF_B  163840

// ---------- prep: pack weights into per-(cg,kk,ai) contiguous 1KB fragments ----------
__global__ void prep_weights(const float* __restrict__ Wrel,
                             const float* __restrict__ Wnode,
                             const float* __restrict__ W1,
                             const float* __restrict__ W2,
                             bf16* __restrict__ ws) {
  int id = blockIdx.x * 256 + threadIdx.x;
  if (id < 32768) {                       // PK1: cg(4) kk(4) ai(4) l(64) j(8)
    int cg = id >> 13, rem = id & 8191;
    int kk = rem >> 11;
    int ai = (rem >> 9) & 3;
    int l  = (rem >> 3) & 63;
    int j  = rem & 7;
    int n  = (cg & 1) * 64 + ai * 16 + (l & 15);
    int k  = kk * 32 + (l >> 4) * 8 + j;
    const float* src = (cg >> 1) ? Wnode : Wrel;
    ws[WS_PK1 + id] = (bf16)src[k * 128 + n];
  } else if (id < 98304) {                // PK2: cg(4) kk(8) ai(4) l(64) j(8)
    int t = id - 32768;
    int cg = t >> 14, rem = t & 16383;
    int kk = rem >> 11;
    int ai = (rem >> 9) & 3;
    int l  = (rem >> 3) & 63;
    int j  = rem & 7;
    int n  = cg * 64 + ai * 16 + (l & 15);
    int k  = kk * 32 + (l >> 4) * 8 + j;
    ws[WS_PK2 + t] = (bf16)W1[k * 256 + n];
  } else if (id < 163840) {               // PK3
    int t = id - 98304;
    int cg = t >> 14, rem = t & 16383;
    int kk = rem >> 11;
    int ai = (rem >> 9) & 3;
    int l  = (rem >> 3) & 63;
    int j  = rem & 7;
    int n  = cg * 64 + ai * 16 + (l & 15);
    int k  = kk * 32 + (l >> 4) * 8 + j;
    ws[WS_PK3 + t] = (bf16)W2[k * 256 + n];
  }
}

// ---------- prep: qg[64][256] = sigmoid(question @ W_qgate), fp32 ----------
__global__ void prep_qg(const float* __restrict__ question,
                        const float* __restrict__ Wq,
                        float* __restrict__ qgf) {
  int b = blockIdx.x, c = threadIdx.x;
  float s = 0.f;
#pragma unroll 8
  for (int k = 0; k < 128; ++k) s += question[b * 128 + k] * Wq[k * 256 + c];
  qgf[b * 256 + c] = 1.f / (1.f + expf(-s));
}

// tanh-form GELU, exp2-direct. max |diff vs erf-GELU| ~5e-4 << 1.23e-2 budget.
__device__ __forceinline__ float gelu_fast(float x) {
  float m = x * x;
  float t = fmaf(0.10294537f, m, 2.30220790f);
  float e = __builtin_amdgcn_exp2f(t * x);
  float r = __builtin_amdgcn_rcpf(e + 1.f);
  return x - x * r;
}

typedef __attribute__((address_space(1))) const void gq_t;
typedef __attribute__((address_space(3))) void lq_t;
#define GLD16(g, s) __builtin_amdgcn_global_load_lds((gq_t*)(g), (lq_t*)(s), 16, 0, 0)
// sched_barrier mask 0xF = ALU|VALU|SALU|MFMA may cross; DS/VMEM pinned.
#define SB() __builtin_amdgcn_sched_barrier(0xF)
#define WAIT_VM4()   { asm volatile("s_waitcnt vmcnt(4)" ::: "memory"); SB(); }
#define WAIT_VM0()   { asm volatile("s_waitcnt vmcnt(0)" ::: "memory"); SB(); }
#define WAIT_LGKM0() { asm volatile("s_waitcnt lgkmcnt(0)" ::: "memory"); SB(); }
#define BAR() __builtin_amdgcn_s_barrier()

// ---------- main: 64 edges/block, 4 waves (1 cg each), 2 blocks/CU ----------
// Champion structure (R12/R19/R23): wave-private 2-slot weight FIFO in LDS
// fed by global_load_lds, depth-2 counted vmcnt (never drained mid-loop);
// swapped-operand MFMA (D = W x X^T); exp2 GELU; fp32 gate table;
// nontemporal rel-token loads + output stores (best timed config, R23).
// R25: tail_idx loads hoisted to kernel top so the 2-hop node gather chain
// starts before the ebatch->gate gather chain (concurrent chain resolution).
__global__ __launch_bounds__(256, 2) void fused_main(
    const float* __restrict__ rel_tok,   // [E,128]
    const float* __restrict__ node_tok,  // [N,128]
    const int*   __restrict__ tail_idx,  // edge_index + E
    const int*   __restrict__ ebatch,    // [E]
    const bf16*  __restrict__ pk1,
    const bf16*  __restrict__ pk2,
    const bf16*  __restrict__ pk3,
    const float* __restrict__ qgf,       // [64][256] fp32
    const float* __restrict__ b1,
    const float* __restrict__ b2,
    float* __restrict__ out)             // [E,256]
{
  // s_buf 32KB union: tokens [2][64][128] bf16 (h*16384 + e*256 + swz)
  //                   AK/H   [64][256]    bf16 (e*512 + swz)
  // s_w   32KB: [slot 2][cg 4][4KB]
  __shared__ char  s_buf[32768];
  __shared__ char  s_w[32768];
  __shared__ float s_bias[512];          // b1 | b2

  const int tid = threadIdx.x;
  const int cg  = tid >> 6;       // wave = col group, cols [cg*64, cg*64+64)
  const int l   = tid & 63;
  const int lo  = l & 15;
  const int hi  = l >> 4;
  const int base = blockIdx.x * 64;
  const int h1  = cg >> 1;        // GEMM1 half (0=rel, 1=node)

  // ---- hoist: first hop of the node-gather chain, issued before anything ----
  int tails[8];
#pragma unroll
  for (int i = 0; i < 8; ++i) tails[i] = tail_idx[base + ((tid + i * 256) >> 5)];

  auto issue_step = [&](int s) {   // s compile-time after unroll
    const bf16* g;
    if (s < 4)       g = pk1 + cg * 8192  + s * 2048;
    else if (s < 12) g = pk2 + cg * 16384 + (s - 4) * 2048;
    else             g = pk3 + cg * 16384 + (s - 12) * 2048;
    g += l * 8;
    char* d = s_w + (s & 1) * 16384 + cg * 4096;
#pragma unroll
    for (int ai = 0; ai < 4; ++ai) GLD16(g + ai * 512, d + ai * 1024);
  };

  // ---- pre-FIFO VMEM: fp32 gate fragments (64 VGPR, dead by B_c), biases -> LDS ----
  int ebv[4];
#pragma unroll
  for (int bj = 0; bj < 4; ++bj) ebv[bj] = ebatch[base + bj * 16 + lo];
  f32x4 gv[4][4];
#pragma unroll
  for (int bj = 0; bj < 4; ++bj)
#pragma unroll
    for (int ai = 0; ai < 4; ++ai)
      gv[bj][ai] = *(const f32x4*)(qgf + ebv[bj] * 256 + cg * 64 + ai * 16 + hi * 4);
  s_bias[tid]       = b1[tid];
  s_bias[256 + tid] = b2[tid];

  // ---- stage tokens -> LDS bf16 ((row&15) XOR swizzle) ----
  {
    const f32x4* g = (const f32x4*)rel_tok + (size_t)base * 32;
#pragma unroll
    for (int i = 0; i < 8; ++i) {
      int idx = tid + i * 256;          // over [64][32] float4
      int row = idx >> 5, c4 = idx & 31;
      f32x4 v = __builtin_nontemporal_load(g + idx);   // read-once stream
      bf16x4 b; b[0] = (bf16)v[0]; b[1] = (bf16)v[1]; b[2] = (bf16)v[2]; b[3] = (bf16)v[3];
      int off = row * 256 + ((c4 * 8) ^ ((row & 15) << 4));
      *(bf16x4*)(s_buf + off) = b;
    }
#pragma unroll
    for (int i = 0; i < 8; ++i) {
      int idx = tid + i * 256;
      int row = idx >> 5, c4 = idx & 31;
      f32x4 v = ((const f32x4*)node_tok)[(size_t)tails[i] * 32 + c4];  // reused: cache normally
      bf16x4 b; b[0] = (bf16)v[0]; b[1] = (bf16)v[1]; b[2] = (bf16)v[2]; b[3] = (bf16)v[3];
      int off = 16384 + row * 256 + ((c4 * 8) ^ ((row & 15) << 4));
      *(bf16x4*)(s_buf + off) = b;
    }
  }

  WAIT_VM0();                           // clean vmcnt slate before FIFO starts
  issue_step(0);
  issue_step(1);
  WAIT_LGKM0();                         // token/bias LDS writes done
  BAR();                                // B_a: tokens + biases visible

  const f32x4 zero4 = {0.f, 0.f, 0.f, 0.f};
  const int wb = cg * 4096 + l * 16;    // lane's read offset within a slot half

  // ================= GEMM1: steps 0..3, b from token region =================
  f32x4 acc1[4][4];
#pragma unroll
  for (int ai = 0; ai < 4; ++ai)
#pragma unroll
    for (int bj = 0; bj < 4; ++bj) acc1[ai][bj] = zero4;

#pragma unroll
  for (int kk = 0; kk < 4; ++kk) {
    const int s = kk;
    WAIT_VM4();                         // step s resident (s+1 in flight)
    bf16x8 a[4];
#pragma unroll
    for (int ai = 0; ai < 4; ++ai)
      a[ai] = *(const bf16x8*)(s_w + (s & 1) * 16384 + wb + ai * 1024);
    WAIT_LGKM0();                       // a[] in regs before slot reuse
    issue_step(s + 2);
    __builtin_amdgcn_s_setprio(1);
#pragma unroll
    for (int bj = 0; bj < 4; ++bj) {
      int e = bj * 16 + lo;
      bf16x8 b = *(const bf16x8*)(s_buf + h1 * 16384 + e * 256 +
                                  ((kk * 64 + hi * 16) ^ ((e & 15) << 4)));
#pragma unroll
      for (int ai = 0; ai < 4; ++ai)
        acc1[ai][bj] = __builtin_amdgcn_mfma_f32_16x16x32_bf16(a[ai], b, acc1[ai][bj], 0, 0, 0);
    }
    __builtin_amdgcn_s_setprio(0);
  }
  BAR();                                // B_b: all token reads done

  // gate + pack -> AK over token buffer (fp32 gate: no cvt)
#pragma unroll
  for (int bj = 0; bj < 4; ++bj) {
    int e = bj * 16 + lo;
#pragma unroll
    for (int ai = 0; ai < 4; ++ai) {
      int col0 = cg * 64 + ai * 16 + hi * 4;
      bf16x4 pk;
      pk[0] = (bf16)(acc1[ai][bj][0] * gv[bj][ai][0]);
      pk[1] = (bf16)(acc1[ai][bj][1] * gv[bj][ai][1]);
      pk[2] = (bf16)(acc1[ai][bj][2] * gv[bj][ai][2]);
      pk[3] = (bf16)(acc1[ai][bj][3] * gv[bj][ai][3]);
      int off = e * 512 + ((2 * col0) ^ ((e & 15) << 4));
      *(bf16x4*)(s_buf + off) = pk;
    }
  }
  WAIT_LGKM0();
  BAR();                                // B_c: AK visible

  // ================= GEMM2: steps 4..11, b from AK =================
  f32x4 acc2[4][4];
#pragma unroll
  for (int ai = 0; ai < 4; ++ai)
#pragma unroll
    for (int bj = 0; bj < 4; ++bj) acc2[ai][bj] = zero4;

#pragma unroll
  for (int kk = 0; kk < 8; ++kk) {
    const int s = 4 + kk;
    WAIT_VM4();
    bf16x8 a[4];
#pragma unroll
    for (int ai = 0; ai < 4; ++ai)
      a[ai] = *(const bf16x8*)(s_w + (s & 1) * 16384 + wb + ai * 1024);
    WAIT_LGKM0();
    issue_step(s + 2);
    __builtin_amdgcn_s_setprio(1);
#pragma unroll
    for (int bj = 0; bj < 4; ++bj) {
      int e = bj * 16 + lo;
      bf16x8 b = *(const bf16x8*)(s_buf + e * 512 +
                                  ((kk * 64 + hi * 16) ^ ((e & 15) << 4)));
#pragma unroll
      for (int ai = 0; ai < 4; ++ai)
        acc2[ai][bj] = __builtin_amdgcn_mfma_f32_16x16x32_bf16(a[ai], b, acc2[ai][bj], 0, 0, 0);
    }
    __builtin_amdgcn_s_setprio(0);
  }
  BAR();                                // B_d: all AK reads done

  // gelu + bias -> H (bias from LDS: no VMEM in FIFO window)
#pragma unroll
  for (int bj = 0; bj < 4; ++bj) {
    int e = bj * 16 + lo;
#pragma unroll
    for (int ai = 0; ai < 4; ++ai) {
      int col0 = cg * 64 + ai * 16 + hi * 4;
      f32x4 bv = *(const f32x4*)(s_bias + col0);
      bf16x4 pk;
      pk[0] = (bf16)gelu_fast(acc2[ai][bj][0] + bv[0]);
      pk[1] = (bf16)gelu_fast(acc2[ai][bj][1] + bv[1]);
      pk[2] = (bf16)gelu_fast(acc2[ai][bj][2] + bv[2]);
      pk[3] = (bf16)gelu_fast(acc2[ai][bj][3] + bv[3]);
      int off = e * 512 + ((2 * col0) ^ ((e & 15) << 4));
      *(bf16x4*)(s_buf + off) = pk;
    }
  }
  WAIT_LGKM0();
  BAR();                                // B_e: H visible

  // ================= GEMM3: steps 12..19, b from H =================
  f32x4 acc3[4][4];
#pragma unroll
  for (int ai = 0; ai < 4; ++ai)
#pragma unroll
    for (int bj = 0; bj < 4; ++bj) acc3[ai][bj] = zero4;

#pragma unroll
  for (int kk = 0; kk < 8; ++kk) {
    const int s = 12 + kk;
    if (s < 19) { WAIT_VM4(); } else { WAIT_VM0(); }
    bf16x8 a[4];
#pragma unroll
    for (int ai = 0; ai < 4; ++ai)
      a[ai] = *(const bf16x8*)(s_w + (s & 1) * 16384 + wb + ai * 1024);
    WAIT_LGKM0();
    if (s + 2 <= 19) issue_step(s + 2);
    __builtin_amdgcn_s_setprio(1);
#pragma unroll
    for (int bj = 0; bj < 4; ++bj) {
      int e = bj * 16 + lo;
      bf16x8 b = *(const bf16x8*)(s_buf + e * 512 +
                                  ((kk * 64 + hi * 16) ^ ((e & 15) << 4)));
#pragma unroll
      for (int ai = 0; ai < 4; ++ai)
        acc3[ai][bj] = __builtin_amdgcn_mfma_f32_16x16x32_bf16(a[ai], b, acc3[ai][bj], 0, 0, 0);
    }
    __builtin_amdgcn_s_setprio(0);
  }

  // bias + store (nontemporal f32x4: out never re-read; best timed config)
#pragma unroll
  for (int bj = 0; bj < 4; ++bj) {
    int e = bj * 16 + lo;
#pragma unroll
    for (int ai = 0; ai < 4; ++ai) {
      int col0 = cg * 64 + ai * 16 + hi * 4;
      f32x4 bv = *(const f32x4*)(s_bias + 256 + col0);
      f32x4 o;
      o[0] = acc3[ai][bj][0] + bv[0];
      o[1] = acc3[ai][bj][1] + bv[1];
      o[2] = acc3[ai][bj][2] + bv[2];
      o[3] = acc3[ai][bj][3] + bv[3];
      __builtin_nontemporal_store(o, (f32x4*)(out + (size_t)(base + e) * 256 + col0));
    }
  }
}

extern "C" void kernel_launch(void* const* d_in, const int* in_sizes, int n_in,
                              void* d_out, int out_size, void* d_ws, size_t ws_size,
                              hipStream_t stream) {
  const float* rel    = (const float*)d_in[0];
  const float* node   = (const float*)d_in[1];
  const int*   eidx   = (const int*)d_in[2];
  const float* quest  = (const float*)d_in[3];
  const int*   ebat   = (const int*)d_in[4];
  const float* Wrel   = (const float*)d_in[5];
  const float* Wnode  = (const float*)d_in[6];
  const float* Wq     = (const float*)d_in[7];
  const float* W1     = (const float*)d_in[8];
  const float* bias1  = (const float*)d_in[9];
  const float* W2     = (const float*)d_in[10];
  const float* bias2  = (const float*)d_in[11];
  float* outp = (float*)d_out;
  bf16* ws = (bf16*)d_ws;
  float* qgf = (float*)(ws + WS_QGF_B);

  const int E = in_sizes[4];  // 400000

  prep_weights<<<640, 256, 0, stream>>>(Wrel, Wnode, W1, W2, ws);
  prep_qg<<<64, 256, 0, stream>>>(quest, Wq, qgf);
  fused_main<<<E / 64, 256, 0, stream>>>(
      rel, node, eidx + E, ebat,
      ws + WS_PK1, ws + WS_PK2, ws + WS_PK3, qgf,
      bias1, bias2, outp);
}